// Round 18
// baseline (293.172 us; speedup 1.0000x reference)
//
#include <hip/hip_runtime.h>

#define HWc   262144   // 512*512
#define CGc   128
#define CHc   64
#define COc   32
#define NPIXc 524288   // B*H*W
#define TW 32
#define TH 8
#define HLW 38         // TW+6
#define HLH 14         // TH+6
#define HPX (HLW*HLH)  // 532

typedef _Float16 h2    __attribute__((ext_vector_type(2)));
typedef __fp16   fp2   __attribute__((ext_vector_type(2)));
typedef _Float16 f16x8 __attribute__((ext_vector_type(8)));
typedef float    f32x4 __attribute__((ext_vector_type(4)));

union AB { uint4 q; f16x8 v; h2 p[4]; unsigned u[4]; };

__device__ __forceinline__ int refl(int p){
  if (p < 0) p = -p;
  else if (p >= 512) p = 1022 - p;
  return p;
}
__device__ __forceinline__ h2 as_h2(unsigned u){ union{unsigned u; h2 h;} x; x.u = u; return x.h; }
__device__ __forceinline__ unsigned as_u(h2 h){ union{unsigned u; h2 h;} x; x.h = h; return x.u; }
__device__ __forceinline__ unsigned pkh(float a, float b){       // RNE pack
  h2 h; h.x = (_Float16)a; h.y = (_Float16)b; return as_u(h);
}
__device__ __forceinline__ h2 pkrtz(float a, float b){           // v_cvt_pkrtz
  union{ fp2 f; h2 h; } x; x.f = __builtin_amdgcn_cvt_pkrtz(a, b); return x.h;
}
__device__ __forceinline__ float2 upk(unsigned u){
  h2 h = as_h2(u); return make_float2((float)h.x, (float)h.y);
}
__device__ __forceinline__ float dot2h(unsigned a, unsigned b, float c){
  return __builtin_amdgcn_fdot2(as_h2(a), as_h2(b), c, false);
}
// packed f16 fma: d = a*b + c on 2 f16 lanes (VOP3P)
__device__ __forceinline__ unsigned pkfma16(unsigned a, unsigned b, unsigned c){
  unsigned d;
  asm("v_pk_fma_f16 %0, %1, %2, %3" : "=v"(d) : "v"(a), "v"(b), "v"(c));
  return d;
}
__device__ __forceinline__ f32x4 mfma32(f16x8 a, f16x8 b, f32x4 c){
  return __builtin_amdgcn_mfma_f32_16x16x32_f16(a, b, c, 0, 0, 0);
}
// async global->LDS, 16B per lane; dest = wave-uniform base + lane*16 (HW)
__device__ __forceinline__ void gload16(const float* g, float* l){
  __builtin_amdgcn_global_load_lds(
      (const __attribute__((address_space(1))) unsigned*)g,
      (__attribute__((address_space(3))) unsigned*)l, 16, 0, 0);
}

// -------- K0: sigma; pack wg and w_sn into MFMA A-fragment order ----------------------
__global__ void k0_prep(const float* __restrict__ wbar, const float* __restrict__ u,
                        const float* __restrict__ wg,
                        unsigned* __restrict__ wgA, unsigned* __restrict__ wsnA){
  const int t = threadIdx.x;
  __shared__ float sv1[32];
  float tv = 0.f;
  if (t < 32){
    #pragma unroll
    for (int o = 0; o < 32; o++) tv += wbar[o*32 + t] * u[o];
  }
  float sq = tv * tv;
  #pragma unroll
  for (int off = 32; off; off >>= 1) sq += __shfl_down(sq, off);
  const float n1 = sqrtf(__shfl(sq, 0)) + 1e-12f;
  if (t < 32) sv1[t] = tv / n1;
  __syncthreads();
  float tu = 0.f;
  if (t < 32){
    #pragma unroll
    for (int c = 0; c < 32; c++) tu += wbar[t*32 + c] * sv1[c];
  }
  float sq2 = tu * tu;
  #pragma unroll
  for (int off = 32; off; off >>= 1) sq2 += __shfl_down(sq2, off);
  const float S = __shfl(sq2, 0);
  const float inv = (sqrtf(S) + 1e-12f) / S;     // 1/sigma

  for (int k = t; k < 4096; k += 64){
    const int mk = k >> 8, L = (k >> 2) & 63, j = k & 3;
    const int m = mk >> 2, ks = mk & 3;
    const int o = m*16 + (L & 15);
    const int c = ks*32 + 8*(L >> 4) + 2*j;
    wgA[k] = pkh(wg[o*128 + c], wg[o*128 + c + 1]);
  }
  for (int k = t; k < 512; k += 64){
    const int m = k >> 8, L = (k >> 2) & 63, j = k & 3;
    const int o = m*16 + (L & 15);
    const int c = 8*(L >> 4) + 2*j;
    wsnA[k] = pkh(wbar[o*32 + c] * inv, wbar[o*32 + c + 1] * inv);
  }
}

// -------- K1m: async global_load_lds staging + MFMA conv/norm/alpha' + apx export -----
__global__ __launch_bounds__(256) void k1m(const float* __restrict__ f,
                                           const float* __restrict__ alpha,
                                           const uint4* __restrict__ wgA,
                                           const uint4* __restrict__ wsnA,
                                           const float* __restrict__ bg,
                                           unsigned* __restrict__ gn,
                                           unsigned* __restrict__ apm,
                                           unsigned* __restrict__ apx){
  __shared__ float ldsf[128 * 64];   // 32 KB: [ch][64 px] f32
  __shared__ float ldsa[32 * 64];    //  8 KB: [ch][64 px] f32

  const int tid  = threadIdx.x;
  const int lane = tid & 63, w = tid >> 6;
  const int lo   = lane & 15, hi = lane >> 4;

  AB wga[4][4];
  #pragma unroll
  for (int m = 0; m < 4; m++)
    #pragma unroll
    for (int ks = 0; ks < 4; ks++)
      wga[m][ks].q = wgA[(m*4 + ks)*64 + lane];
  AB wsa[2];
  #pragma unroll
  for (int m = 0; m < 2; m++) wsa[m].q = wsnA[m*64 + lane];
  float4 bgl[4];
  #pragma unroll
  for (int m = 0; m < 4; m++) bgl[m] = *(const float4*)(bg + m*16 + hi*4);

  const int px0  = blockIdx.x * 256;
  const int b    = px0 >> 18;
  const int pix0 = px0 & (HWc - 1);
  const float* fbase = f + (size_t)b * CGc * HWc;
  const float* abase = alpha + (size_t)b * COc * HWc;

  #pragma unroll 1
  for (int h = 0; h < 4; h++){
    const int pbase = pix0 + h*64;

    // ---- async stage: each instr fills 4 ch-rows (1 KB), lane -> ch/px linear ----
    {
      const int cf0 = w * 32;                    // this wave's 32 f channels
      #pragma unroll
      for (int k = 0; k < 8; k++){
        const int c0 = cf0 + k*4;
        const float* src = fbase + (size_t)(c0 + (lane >> 4)) * HWc + pbase + (lane & 15)*4;
        gload16(src, &ldsf[c0 * 64]);
      }
      const int ca0 = w * 8;                     // this wave's 8 alpha channels
      #pragma unroll
      for (int k = 0; k < 2; k++){
        const int c0 = ca0 + k*4;
        const float* src = abase + (size_t)(c0 + (lane >> 4)) * HWc + pbase + (lane & 15)*4;
        gload16(src, &ldsa[c0 * 64]);
      }
    }
    asm volatile("s_waitcnt vmcnt(0)" ::: "memory");
    __syncthreads();

    // ---- compute: wave w -> one 16-px MFMA tile ----
    const int pxl = w*16 + lo;                   // local px in [0,64)
    const int pxg = px0 + h*64 + w*16;           // global tile base

    f32x4 acc[4];
    #pragma unroll
    for (int m = 0; m < 4; m++) acc[m] = (f32x4){0.f, 0.f, 0.f, 0.f};

    #pragma unroll
    for (int ks = 0; ks < 4; ks++){
      AB bf;
      #pragma unroll
      for (int j = 0; j < 4; j++){
        const int ch = ks*32 + hi*8 + 2*j;
        bf.p[j] = pkrtz(ldsf[ch*64 + pxl], ldsf[(ch + 1)*64 + pxl]);
      }
      #pragma unroll
      for (int m = 0; m < 4; m++)
        acc[m] = mfma32(wga[m][ks].v, bf.v, acc[m]);
    }

    float v[16]; float nsq = 0.f;
    #pragma unroll
    for (int m = 0; m < 4; m++){
      v[4*m+0] = acc[m][0] + bgl[m].x;
      v[4*m+1] = acc[m][1] + bgl[m].y;
      v[4*m+2] = acc[m][2] + bgl[m].z;
      v[4*m+3] = acc[m][3] + bgl[m].w;
      nsq = fmaf(v[4*m+0], v[4*m+0], nsq); nsq = fmaf(v[4*m+1], v[4*m+1], nsq);
      nsq = fmaf(v[4*m+2], v[4*m+2], nsq); nsq = fmaf(v[4*m+3], v[4*m+3], nsq);
    }
    nsq += __shfl_xor(nsq, 16);
    nsq += __shfl_xor(nsq, 32);
    const float inv = 1.f / fmaxf(sqrtf(nsq), 1e-4f);

    unsigned* gp = gn + (size_t)(pxg + lo) * 32 + hi*2;
    #pragma unroll
    for (int m = 0; m < 4; m++){
      uint2 st = make_uint2(pkh(v[4*m+0]*inv, v[4*m+1]*inv),
                            pkh(v[4*m+2]*inv, v[4*m+3]*inv));
      *(uint2*)(gp + m*8) = st;
    }

    AB af;
    #pragma unroll
    for (int j = 0; j < 4; j++){
      const int ch = hi*8 + 2*j;
      af.p[j] = pkrtz(ldsa[ch*64 + pxl], ldsa[(ch + 1)*64 + pxl]);
    }
    // export raw alpha as pixel-major f16 for K4 (residual add): 4x f16-pairs per thread
    *(uint4*)(apx + (size_t)(pxg + lo) * 16 + hi*4) = af.q;

    unsigned* op = apm + (size_t)(pxg + lo) * 16 + hi*2;
    #pragma unroll
    for (int m = 0; m < 2; m++){
      f32x4 aa = (f32x4){0.f, 0.f, 0.f, 0.f};
      aa = mfma32(wsa[m].v, af.v, aa);
      uint2 st = make_uint2(pkh(aa[0], aa[1]), pkh(aa[2], aa[3]));
      *(uint2*)(op + m*8) = st;
    }
    __syncthreads();   // LDS reuse by next half
  }
}

// -------- K2: dot2 correlation + softmax + pk_fma_f16 aggregation -> y2 f16 ----------
__global__ __launch_bounds__(256) void k2_agg(const unsigned* __restrict__ gn,
                                              const unsigned* __restrict__ apm,
                                              unsigned* __restrict__ y2){
  __shared__ uint4 gs4[8][HPX];   // 68 KB: full halo, 8 channel-pair planes

  const int lb  = (blockIdx.x & 7) * 256 + (blockIdx.x >> 3);   // XCD-chunked swizzle
  const int txx = lb & 15;
  const int tyy = (lb >> 4) & 63;
  const int bb  = lb >> 10;
  const int x0  = txx * TW, y0 = tyy * TH;
  const int tid = threadIdx.x;

  for (int t = tid; t < HPX; t += 256){
    const int hr = t / HLW;
    const int hc = t - hr * HLW;
    const int gy = refl(y0 + hr - 3);
    const int gx = refl(x0 + hc - 3);
    const uint4* src = (const uint4*)(gn + (size_t)((bb << 18) + (gy << 9) + gx) * 32);
    #pragma unroll
    for (int k = 0; k < 8; k++) gs4[k][t] = src[k];
  }
  __syncthreads();

  const int r  = tid >> 5, c = tid & 31;
  const int yy = y0 + r,  xx = x0 + c;
  const int self = (r + 3) * HLW + (c + 3);

  uint4 cv[8];
  #pragma unroll
  for (int k = 0; k < 8; k++) cv[k] = gs4[k][self];

  int ax[7];
  #pragma unroll
  for (int j = 0; j < 7; j++) ax[j] = refl(xx + j - 3);

  unsigned ya[16];   // 32 channels as f16 pairs
  #pragma unroll
  for (int k = 0; k < 16; k++) ya[k] = 0u;
  float esum = 0.f;

  #pragma unroll 1
  for (int i = 0; i < 7; i++){
    const int ay = refl(yy + i - 3);
    const unsigned* aprow = apm + (size_t)((bb << 18) + (ay << 9)) * 16;
    const int rowbase = (r + i) * HLW + c;
    #pragma unroll
    for (int j = 0; j < 7; j++){
      if (i == 3 && j == 3) continue;          // center tap: exp(-10000) == 0
      const int hp = rowbase + j;
      float s0 = 0.f, s1 = 0.f, s2 = 0.f, s3 = 0.f;
      #pragma unroll
      for (int k = 0; k < 8; k++){
        const uint4 q = gs4[k][hp];
        s0 = dot2h(cv[k].x, q.x, s0);
        s1 = dot2h(cv[k].y, q.y, s1);
        s2 = dot2h(cv[k].z, q.z, s2);
        s3 = dot2h(cv[k].w, q.w, s3);
      }
      const float e = __expf((s0 + s1) + (s2 + s3));
      esum += e;
      const unsigned eh = as_u(pkrtz(e, e));   // e broadcast to both f16 lanes
      const uint4* ap = (const uint4*)(aprow + (size_t)ax[j] * 16);
      #pragma unroll
      for (int kk = 0; kk < 4; kk++){
        const uint4 a = ap[kk];
        ya[4*kk+0] = pkfma16(a.x, eh, ya[4*kk+0]);
        ya[4*kk+1] = pkfma16(a.y, eh, ya[4*kk+1]);
        ya[4*kk+2] = pkfma16(a.z, eh, ya[4*kk+2]);
        ya[4*kk+3] = pkfma16(a.w, eh, ya[4*kk+3]);
      }
    }
  }

  const float inv = 1.f / esum;
  unsigned yw[16];
  #pragma unroll
  for (int k = 0; k < 16; k++){
    const float2 t2 = upk(ya[k]);
    yw[k] = pkh(t2.x * inv, t2.y * inv);
  }
  uint4* yp = (uint4*)(y2 + (size_t)((bb << 18) + (yy << 9) + xx) * 16);
  #pragma unroll
  for (int k = 0; k < 4; k++)
    yp[k] = make_uint4(yw[4*k], yw[4*k+1], yw[4*k+2], yw[4*k+3]);
}

// -------- K3: BN stats over f16 y2 ---------------------------------------------------
__global__ __launch_bounds__(256) void k3_stats(const unsigned* __restrict__ y2,
                                                float* __restrict__ stats){
  float s[COc], q[COc];
  #pragma unroll
  for (int o = 0; o < COc; o++){ s[o] = 0.f; q[o] = 0.f; }
  const int stride = gridDim.x * 256;
  for (int p = blockIdx.x * 256 + threadIdx.x; p < NPIXc; p += stride){
    const uint4* yp = (const uint4*)(y2 + (size_t)p * 16);
    #pragma unroll
    for (int k = 0; k < 4; k++){
      const uint4 w = yp[k];
      const unsigned vv[4] = {w.x, w.y, w.z, w.w};
      #pragma unroll
      for (int m = 0; m < 4; m++){
        const float2 ab = upk(vv[m]);
        s[8*k+2*m]   += ab.x; q[8*k+2*m]   = fmaf(ab.x, ab.x, q[8*k+2*m]);
        s[8*k+2*m+1] += ab.y; q[8*k+2*m+1] = fmaf(ab.y, ab.y, q[8*k+2*m+1]);
      }
    }
  }
  #pragma unroll
  for (int o = 0; o < COc; o++){
    #pragma unroll
    for (int off = 32; off; off >>= 1){
      s[o] += __shfl_down(s[o], off);
      q[o] += __shfl_down(q[o], off);
    }
  }
  __shared__ float red[4][64];
  const int wv = threadIdx.x >> 6;
  if ((threadIdx.x & 63) == 0){
    #pragma unroll
    for (int o = 0; o < COc; o++){ red[wv][o] = s[o]; red[wv][32 + o] = q[o]; }
  }
  __syncthreads();
  if (threadIdx.x < 64){
    const float v = red[0][threadIdx.x] + red[1][threadIdx.x]
                  + red[2][threadIdx.x] + red[3][threadIdx.x];
    atomicAdd(&stats[threadIdx.x], v);
  }
}

// -------- K3b: stats -> (mean, 0.1*rsqrt(var+eps)) ------------------------------------
__global__ void k3b_final(const float* __restrict__ stats, float* __restrict__ stats2){
  const int t = threadIdx.x;
  if (t < COc){
    const float invN = 1.f / (float)NPIXc;
    const float mean = stats[t] * invN;
    const float var  = fmaf(-mean, mean, stats[COc + t] * invN);
    stats2[t]       = mean;
    stats2[COc + t] = 0.1f * rsqrtf(var + 1e-5f);
  }
}

// -------- K4: BatchNorm + residual (alpha from pixel-major f16 apx) -------------------
__global__ __launch_bounds__(256) void k4_out(const unsigned* __restrict__ y2,
                                              const unsigned* __restrict__ apx,
                                              const float* __restrict__ stats2,
                                              float* __restrict__ out){
  const int p   = blockIdx.x * 256 + threadIdx.x;
  const int b   = p >> 18;
  const int pix = p & (HWc - 1);
  const uint4* yp = (const uint4*)(y2 + (size_t)p * 16);
  const uint4* ap = (const uint4*)(apx + (size_t)p * 16);
  const size_t boff = (size_t)b * COc * HWc + pix;
  #pragma unroll
  for (int k = 0; k < 4; k++){
    const uint4 w = yp[k];
    const uint4 a = ap[k];
    const unsigned vv[4] = {w.x, w.y, w.z, w.w};
    const unsigned aa[4] = {a.x, a.y, a.z, a.w};
    #pragma unroll
    for (int m = 0; m < 4; m++){
      const int o = 8*k + 2*m;
      const float2 yv = upk(vv[m]);
      const float2 av = upk(aa[m]);
      out[boff + (size_t)o*HWc]     = fmaf(yv.x - stats2[o],   stats2[COc+o],   av.x);
      out[boff + (size_t)(o+1)*HWc] = fmaf(yv.y - stats2[o+1], stats2[COc+o+1], av.y);
    }
  }
}

extern "C" void kernel_launch(void* const* d_in, const int* in_sizes, int n_in,
                              void* d_out, int out_size, void* d_ws, size_t ws_size,
                              hipStream_t stream){
  const float* f     = (const float*)d_in[0];
  const float* alpha = (const float*)d_in[1];
  const float* wg    = (const float*)d_in[2];
  const float* bg    = (const float*)d_in[3];
  const float* wbar  = (const float*)d_in[4];
  const float* u     = (const float*)d_in[5];
  (void)in_sizes; (void)n_in; (void)out_size; (void)ws_size;
  float* out = (float*)d_out;

  char* ws = (char*)d_ws;
  float*    stats  = (float*)ws;                       // 256 B
  float*    stats2 = (float*)(ws + 4096);              // 256 B
  unsigned* wgA    = (unsigned*)(ws + 8192);           // 16 KB
  unsigned* wsnA   = (unsigned*)(ws + 32768);          // 2 KB
  unsigned* apm    = (unsigned*)(ws + 65536);                                        // 32 MB
  unsigned* gn     = (unsigned*)(ws + 65536 + (size_t)NPIXc*64);                     // 64 MB
  unsigned* y2     = (unsigned*)(ws + 65536 + (size_t)NPIXc*64 + (size_t)NPIXc*128); // 32 MB
  unsigned* apx    = (unsigned*)(ws + 65536 + (size_t)NPIXc*64 + (size_t)NPIXc*128
                                 + (size_t)NPIXc*64);                                // 32 MB

  (void)hipMemsetAsync(stats, 0, 64 * sizeof(float), stream);
  k0_prep  <<<1, 64, 0, stream>>>(wbar, u, wg, wgA, wsnA);
  k1m      <<<NPIXc / 256, 256, 0, stream>>>(f, alpha, (const uint4*)wgA,
                                             (const uint4*)wsnA, bg, gn, apm, apx);
  k2_agg   <<<2048, 256, 0, stream>>>(gn, apm, y2);
  k3_stats <<<256, 256, 0, stream>>>(y2, stats);
  k3b_final<<<1, 64, 0, stream>>>(stats, stats2);
  k4_out   <<<NPIXc / 256, 256, 0, stream>>>(y2, apx, stats2, out);
}

// Round 19
// 287.188 us; speedup vs baseline: 1.0208x; 1.0208x over previous
//
#include <hip/hip_runtime.h>

#define HWc   262144   // 512*512
#define CGc   128
#define CHc   64
#define COc   32
#define NPIXc 524288   // B*H*W
#define TW 32
#define TH 8
#define HLW 38         // TW+6
#define HLH 14         // TH+6
#define HPX (HLW*HLH)  // 532

typedef _Float16 h2    __attribute__((ext_vector_type(2)));
typedef __fp16   fp2   __attribute__((ext_vector_type(2)));
typedef _Float16 f16x8 __attribute__((ext_vector_type(8)));
typedef float    f32x4 __attribute__((ext_vector_type(4)));

union AB { uint4 q; f16x8 v; h2 p[4]; unsigned u[4]; };

__device__ __forceinline__ int refl(int p){
  if (p < 0) p = -p;
  else if (p >= 512) p = 1022 - p;
  return p;
}
__device__ __forceinline__ h2 as_h2(unsigned u){ union{unsigned u; h2 h;} x; x.u = u; return x.h; }
__device__ __forceinline__ unsigned as_u(h2 h){ union{unsigned u; h2 h;} x; x.h = h; return x.u; }
__device__ __forceinline__ unsigned pkh(float a, float b){       // RNE pack
  h2 h; h.x = (_Float16)a; h.y = (_Float16)b; return as_u(h);
}
__device__ __forceinline__ h2 pkrtz(float a, float b){           // v_cvt_pkrtz
  union{ fp2 f; h2 h; } x; x.f = __builtin_amdgcn_cvt_pkrtz(a, b); return x.h;
}
__device__ __forceinline__ float2 upk(unsigned u){
  h2 h = as_h2(u); return make_float2((float)h.x, (float)h.y);
}
__device__ __forceinline__ float dot2h(unsigned a, unsigned b, float c){
  return __builtin_amdgcn_fdot2(as_h2(a), as_h2(b), c, false);
}
// packed f16 fma: d = a*b + c on 2 f16 lanes (VOP3P)
__device__ __forceinline__ unsigned pkfma16(unsigned a, unsigned b, unsigned c){
  unsigned d;
  asm("v_pk_fma_f16 %0, %1, %2, %3" : "=v"(d) : "v"(a), "v"(b), "v"(c));
  return d;
}
__device__ __forceinline__ f32x4 mfma32(f16x8 a, f16x8 b, f32x4 c){
  return __builtin_amdgcn_mfma_f32_16x16x32_f16(a, b, c, 0, 0, 0);
}
// async global->LDS, 16B per lane; dest = wave-uniform base + lane*16 (HW)
__device__ __forceinline__ void gload16(const float* g, float* l){
  __builtin_amdgcn_global_load_lds(
      (const __attribute__((address_space(1))) unsigned*)g,
      (__attribute__((address_space(3))) unsigned*)l, 16, 0, 0);
}

// -------- K0: sigma; pack wg and w_sn into MFMA A-fragment order ----------------------
__global__ void k0_prep(const float* __restrict__ wbar, const float* __restrict__ u,
                        const float* __restrict__ wg,
                        unsigned* __restrict__ wgA, unsigned* __restrict__ wsnA){
  const int t = threadIdx.x;
  __shared__ float sv1[32];
  float tv = 0.f;
  if (t < 32){
    #pragma unroll
    for (int o = 0; o < 32; o++) tv += wbar[o*32 + t] * u[o];
  }
  float sq = tv * tv;
  #pragma unroll
  for (int off = 32; off; off >>= 1) sq += __shfl_down(sq, off);
  const float n1 = sqrtf(__shfl(sq, 0)) + 1e-12f;
  if (t < 32) sv1[t] = tv / n1;
  __syncthreads();
  float tu = 0.f;
  if (t < 32){
    #pragma unroll
    for (int c = 0; c < 32; c++) tu += wbar[t*32 + c] * sv1[c];
  }
  float sq2 = tu * tu;
  #pragma unroll
  for (int off = 32; off; off >>= 1) sq2 += __shfl_down(sq2, off);
  const float S = __shfl(sq2, 0);
  const float inv = (sqrtf(S) + 1e-12f) / S;     // 1/sigma

  for (int k = t; k < 4096; k += 64){
    const int mk = k >> 8, L = (k >> 2) & 63, j = k & 3;
    const int m = mk >> 2, ks = mk & 3;
    const int o = m*16 + (L & 15);
    const int c = ks*32 + 8*(L >> 4) + 2*j;
    wgA[k] = pkh(wg[o*128 + c], wg[o*128 + c + 1]);
  }
  for (int k = t; k < 512; k += 64){
    const int m = k >> 8, L = (k >> 2) & 63, j = k & 3;
    const int o = m*16 + (L & 15);
    const int c = 8*(L >> 4) + 2*j;
    wsnA[k] = pkh(wbar[o*32 + c] * inv, wbar[o*32 + c + 1] * inv);
  }
}

// -------- K1m: async global_load_lds staging (f32 in LDS) + MFMA conv/norm/alpha' -----
__global__ __launch_bounds__(256) void k1m(const float* __restrict__ f,
                                           const float* __restrict__ alpha,
                                           const uint4* __restrict__ wgA,
                                           const uint4* __restrict__ wsnA,
                                           const float* __restrict__ bg,
                                           unsigned* __restrict__ gn,
                                           unsigned* __restrict__ apm){
  __shared__ float ldsf[128 * 64];   // 32 KB: [ch][64 px] f32
  __shared__ float ldsa[32 * 64];    //  8 KB: [ch][64 px] f32

  const int tid  = threadIdx.x;
  const int lane = tid & 63, w = tid >> 6;
  const int lo   = lane & 15, hi = lane >> 4;

  AB wga[4][4];
  #pragma unroll
  for (int m = 0; m < 4; m++)
    #pragma unroll
    for (int ks = 0; ks < 4; ks++)
      wga[m][ks].q = wgA[(m*4 + ks)*64 + lane];
  AB wsa[2];
  #pragma unroll
  for (int m = 0; m < 2; m++) wsa[m].q = wsnA[m*64 + lane];
  float4 bgl[4];
  #pragma unroll
  for (int m = 0; m < 4; m++) bgl[m] = *(const float4*)(bg + m*16 + hi*4);

  const int px0  = blockIdx.x * 256;
  const int b    = px0 >> 18;
  const int pix0 = px0 & (HWc - 1);
  const float* fbase = f + (size_t)b * CGc * HWc;
  const float* abase = alpha + (size_t)b * COc * HWc;

  #pragma unroll 1
  for (int h = 0; h < 4; h++){
    const int pbase = pix0 + h*64;

    // ---- async stage: each instr fills 4 ch-rows (1 KB), lane -> ch/px linear ----
    {
      const int cf0 = w * 32;                    // this wave's 32 f channels
      #pragma unroll
      for (int k = 0; k < 8; k++){
        const int c0 = cf0 + k*4;
        const float* src = fbase + (size_t)(c0 + (lane >> 4)) * HWc + pbase + (lane & 15)*4;
        gload16(src, &ldsf[c0 * 64]);
      }
      const int ca0 = w * 8;                     // this wave's 8 alpha channels
      #pragma unroll
      for (int k = 0; k < 2; k++){
        const int c0 = ca0 + k*4;
        const float* src = abase + (size_t)(c0 + (lane >> 4)) * HWc + pbase + (lane & 15)*4;
        gload16(src, &ldsa[c0 * 64]);
      }
    }
    asm volatile("s_waitcnt vmcnt(0)" ::: "memory");
    __syncthreads();

    // ---- compute: wave w -> one 16-px MFMA tile ----
    const int pxl = w*16 + lo;                   // local px in [0,64)
    const int pxg = px0 + h*64 + w*16;           // global tile base

    f32x4 acc[4];
    #pragma unroll
    for (int m = 0; m < 4; m++) acc[m] = (f32x4){0.f, 0.f, 0.f, 0.f};

    #pragma unroll
    for (int ks = 0; ks < 4; ks++){
      AB bf;
      #pragma unroll
      for (int j = 0; j < 4; j++){
        const int ch = ks*32 + hi*8 + 2*j;
        bf.p[j] = pkrtz(ldsf[ch*64 + pxl], ldsf[(ch + 1)*64 + pxl]);
      }
      #pragma unroll
      for (int m = 0; m < 4; m++)
        acc[m] = mfma32(wga[m][ks].v, bf.v, acc[m]);
    }

    float v[16]; float nsq = 0.f;
    #pragma unroll
    for (int m = 0; m < 4; m++){
      v[4*m+0] = acc[m][0] + bgl[m].x;
      v[4*m+1] = acc[m][1] + bgl[m].y;
      v[4*m+2] = acc[m][2] + bgl[m].z;
      v[4*m+3] = acc[m][3] + bgl[m].w;
      nsq = fmaf(v[4*m+0], v[4*m+0], nsq); nsq = fmaf(v[4*m+1], v[4*m+1], nsq);
      nsq = fmaf(v[4*m+2], v[4*m+2], nsq); nsq = fmaf(v[4*m+3], v[4*m+3], nsq);
    }
    nsq += __shfl_xor(nsq, 16);
    nsq += __shfl_xor(nsq, 32);
    const float inv = 1.f / fmaxf(sqrtf(nsq), 1e-4f);

    unsigned* gp = gn + (size_t)(pxg + lo) * 32 + hi*2;
    #pragma unroll
    for (int m = 0; m < 4; m++){
      uint2 st = make_uint2(pkh(v[4*m+0]*inv, v[4*m+1]*inv),
                            pkh(v[4*m+2]*inv, v[4*m+3]*inv));
      *(uint2*)(gp + m*8) = st;
    }

    AB af;
    #pragma unroll
    for (int j = 0; j < 4; j++){
      const int ch = hi*8 + 2*j;
      af.p[j] = pkrtz(ldsa[ch*64 + pxl], ldsa[(ch + 1)*64 + pxl]);
    }
    unsigned* op = apm + (size_t)(pxg + lo) * 16 + hi*2;
    #pragma unroll
    for (int m = 0; m < 2; m++){
      f32x4 aa = (f32x4){0.f, 0.f, 0.f, 0.f};
      aa = mfma32(wsa[m].v, af.v, aa);
      uint2 st = make_uint2(pkh(aa[0], aa[1]), pkh(aa[2], aa[3]));
      *(uint2*)(op + m*8) = st;
    }
    __syncthreads();   // LDS reuse by next half
  }
}

// -------- K2: dot2 correlation + softmax + pk_fma_f16 aggregation -> y2 f16 ----------
__global__ __launch_bounds__(256) void k2_agg(const unsigned* __restrict__ gn,
                                              const unsigned* __restrict__ apm,
                                              unsigned* __restrict__ y2){
  __shared__ uint4 gs4[8][HPX];   // 68 KB: full halo, 8 channel-pair planes

  const int lb  = (blockIdx.x & 7) * 256 + (blockIdx.x >> 3);   // XCD-chunked swizzle
  const int txx = lb & 15;
  const int tyy = (lb >> 4) & 63;
  const int bb  = lb >> 10;
  const int x0  = txx * TW, y0 = tyy * TH;
  const int tid = threadIdx.x;

  for (int t = tid; t < HPX; t += 256){
    const int hr = t / HLW;
    const int hc = t - hr * HLW;
    const int gy = refl(y0 + hr - 3);
    const int gx = refl(x0 + hc - 3);
    const uint4* src = (const uint4*)(gn + (size_t)((bb << 18) + (gy << 9) + gx) * 32);
    #pragma unroll
    for (int k = 0; k < 8; k++) gs4[k][t] = src[k];
  }
  __syncthreads();

  const int r  = tid >> 5, c = tid & 31;
  const int yy = y0 + r,  xx = x0 + c;
  const int self = (r + 3) * HLW + (c + 3);

  uint4 cv[8];
  #pragma unroll
  for (int k = 0; k < 8; k++) cv[k] = gs4[k][self];

  int ax[7];
  #pragma unroll
  for (int j = 0; j < 7; j++) ax[j] = refl(xx + j - 3);

  unsigned ya[16];   // 32 channels as f16 pairs
  #pragma unroll
  for (int k = 0; k < 16; k++) ya[k] = 0u;
  float esum = 0.f;

  #pragma unroll 1
  for (int i = 0; i < 7; i++){
    const int ay = refl(yy + i - 3);
    const unsigned* aprow = apm + (size_t)((bb << 18) + (ay << 9)) * 16;
    const int rowbase = (r + i) * HLW + c;
    #pragma unroll
    for (int j = 0; j < 7; j++){
      if (i == 3 && j == 3) continue;          // center tap: exp(-10000) == 0
      const int hp = rowbase + j;
      float s0 = 0.f, s1 = 0.f, s2 = 0.f, s3 = 0.f;
      #pragma unroll
      for (int k = 0; k < 8; k++){
        const uint4 q = gs4[k][hp];
        s0 = dot2h(cv[k].x, q.x, s0);
        s1 = dot2h(cv[k].y, q.y, s1);
        s2 = dot2h(cv[k].z, q.z, s2);
        s3 = dot2h(cv[k].w, q.w, s3);
      }
      const float e = __expf((s0 + s1) + (s2 + s3));
      esum += e;
      const unsigned eh = as_u(pkrtz(e, e));   // e broadcast to both f16 lanes
      const uint4* ap = (const uint4*)(aprow + (size_t)ax[j] * 16);
      #pragma unroll
      for (int kk = 0; kk < 4; kk++){
        const uint4 a = ap[kk];
        ya[4*kk+0] = pkfma16(a.x, eh, ya[4*kk+0]);
        ya[4*kk+1] = pkfma16(a.y, eh, ya[4*kk+1]);
        ya[4*kk+2] = pkfma16(a.z, eh, ya[4*kk+2]);
        ya[4*kk+3] = pkfma16(a.w, eh, ya[4*kk+3]);
      }
    }
  }

  const float inv = 1.f / esum;
  unsigned yw[16];
  #pragma unroll
  for (int k = 0; k < 16; k++){
    const float2 t2 = upk(ya[k]);
    yw[k] = pkh(t2.x * inv, t2.y * inv);
  }
  uint4* yp = (uint4*)(y2 + (size_t)((bb << 18) + (yy << 9) + xx) * 16);
  #pragma unroll
  for (int k = 0; k < 4; k++)
    yp[k] = make_uint4(yw[4*k], yw[4*k+1], yw[4*k+2], yw[4*k+3]);
}

// -------- K3: BN stats over f16 y2 ---------------------------------------------------
__global__ __launch_bounds__(256) void k3_stats(const unsigned* __restrict__ y2,
                                                float* __restrict__ stats){
  float s[COc], q[COc];
  #pragma unroll
  for (int o = 0; o < COc; o++){ s[o] = 0.f; q[o] = 0.f; }
  const int stride = gridDim.x * 256;
  for (int p = blockIdx.x * 256 + threadIdx.x; p < NPIXc; p += stride){
    const uint4* yp = (const uint4*)(y2 + (size_t)p * 16);
    #pragma unroll
    for (int k = 0; k < 4; k++){
      const uint4 w = yp[k];
      const unsigned vv[4] = {w.x, w.y, w.z, w.w};
      #pragma unroll
      for (int m = 0; m < 4; m++){
        const float2 ab = upk(vv[m]);
        s[8*k+2*m]   += ab.x; q[8*k+2*m]   = fmaf(ab.x, ab.x, q[8*k+2*m]);
        s[8*k+2*m+1] += ab.y; q[8*k+2*m+1] = fmaf(ab.y, ab.y, q[8*k+2*m+1]);
      }
    }
  }
  #pragma unroll
  for (int o = 0; o < COc; o++){
    #pragma unroll
    for (int off = 32; off; off >>= 1){
      s[o] += __shfl_down(s[o], off);
      q[o] += __shfl_down(q[o], off);
    }
  }
  __shared__ float red[4][64];
  const int wv = threadIdx.x >> 6;
  if ((threadIdx.x & 63) == 0){
    #pragma unroll
    for (int o = 0; o < COc; o++){ red[wv][o] = s[o]; red[wv][32 + o] = q[o]; }
  }
  __syncthreads();
  if (threadIdx.x < 64){
    const float v = red[0][threadIdx.x] + red[1][threadIdx.x]
                  + red[2][threadIdx.x] + red[3][threadIdx.x];
    atomicAdd(&stats[threadIdx.x], v);
  }
}

// -------- K3b: stats -> (mean, 0.1*rsqrt(var+eps)) ------------------------------------
__global__ void k3b_final(const float* __restrict__ stats, float* __restrict__ stats2){
  const int t = threadIdx.x;
  if (t < COc){
    const float invN = 1.f / (float)NPIXc;
    const float mean = stats[t] * invN;
    const float var  = fmaf(-mean, mean, stats[COc + t] * invN);
    stats2[t]       = mean;
    stats2[COc + t] = 0.1f * rsqrtf(var + 1e-5f);
  }
}

// -------- K4: BatchNorm + residual ----------------------------------------------------
__global__ __launch_bounds__(256) void k4_out(const unsigned* __restrict__ y2,
                                              const float* __restrict__ alpha,
                                              const float* __restrict__ stats2,
                                              float* __restrict__ out){
  const int p   = blockIdx.x * 256 + threadIdx.x;
  const int b   = p >> 18;
  const int pix = p & (HWc - 1);
  const uint4* yp = (const uint4*)(y2 + (size_t)p * 16);
  const size_t boff = (size_t)b * COc * HWc + pix;
  #pragma unroll
  for (int k = 0; k < 4; k++){
    const uint4 w = yp[k];
    const unsigned vv[4] = {w.x, w.y, w.z, w.w};
    #pragma unroll
    for (int m = 0; m < 4; m++){
      const int o = 8*k + 2*m;
      const float2 ab = upk(vv[m]);
      out[boff + (size_t)o*HWc]     = fmaf(ab.x - stats2[o],   stats2[COc+o],
                                           alpha[boff + (size_t)o*HWc]);
      out[boff + (size_t)(o+1)*HWc] = fmaf(ab.y - stats2[o+1], stats2[COc+o+1],
                                           alpha[boff + (size_t)(o+1)*HWc]);
    }
  }
}

extern "C" void kernel_launch(void* const* d_in, const int* in_sizes, int n_in,
                              void* d_out, int out_size, void* d_ws, size_t ws_size,
                              hipStream_t stream){
  const float* f     = (const float*)d_in[0];
  const float* alpha = (const float*)d_in[1];
  const float* wg    = (const float*)d_in[2];
  const float* bg    = (const float*)d_in[3];
  const float* wbar  = (const float*)d_in[4];
  const float* u     = (const float*)d_in[5];
  (void)in_sizes; (void)n_in; (void)out_size; (void)ws_size;
  float* out = (float*)d_out;

  char* ws = (char*)d_ws;
  float*    stats  = (float*)ws;                       // 256 B
  float*    stats2 = (float*)(ws + 4096);              // 256 B
  unsigned* wgA    = (unsigned*)(ws + 8192);           // 16 KB
  unsigned* wsnA   = (unsigned*)(ws + 32768);          // 2 KB
  unsigned* apm    = (unsigned*)(ws + 65536);                                   // 32 MB
  unsigned* gn     = (unsigned*)(ws + 65536 + (size_t)NPIXc*64);                // 64 MB
  unsigned* y2     = (unsigned*)(ws + 65536 + (size_t)NPIXc*64 + (size_t)NPIXc*128); // 32 MB

  (void)hipMemsetAsync(stats, 0, 64 * sizeof(float), stream);
  k0_prep  <<<1, 64, 0, stream>>>(wbar, u, wg, wgA, wsnA);
  k1m      <<<NPIXc / 256, 256, 0, stream>>>(f, alpha, (const uint4*)wgA,
                                             (const uint4*)wsnA, bg, gn, apm);
  k2_agg   <<<2048, 256, 0, stream>>>(gn, apm, y2);
  k3_stats <<<256, 256, 0, stream>>>(y2, stats);
  k3b_final<<<1, 64, 0, stream>>>(stats, stats2);
  k4_out   <<<NPIXc / 256, 256, 0, stream>>>(y2, alpha, stats2, out);
}